// Round 1
// baseline (373.280 us; speedup 1.0000x reference)
//
#include <hip/hip_runtime.h>

#define BB 2
#define CC 2
#define NN 1024
#define HH 8
#define BCHN 32
#define SVN (BCHN*NN)
#define NBLK 512
#define LOG2E 1.44269504f

typedef _Float16 f16x8 __attribute__((ext_vector_type(8)));
typedef _Float16 f16x4 __attribute__((ext_vector_type(4)));
typedef __fp16 h16x2 __attribute__((ext_vector_type(2)));
typedef float f32x4 __attribute__((ext_vector_type(4)));

union SmemU {
  _Float16 tile[64*72];                                   // prep transpose staging (9.2 KB)
  struct { float sp[4][32]; float sd[4][32]; } pr;        // proj reductions (1 KB)
  struct { float partials[4][32*68]; float dsP[4][32]; } at; // attn epilogue (35.3 KB)
};

__device__ __forceinline__ float fexp2(float x) {
  float r; asm("v_exp_f32 %0, %1" : "=v"(r) : "v"(x)); return r;
}

// Device-scope grid barrier: counter runs monotonically (g-th barrier waits for g*NBLK
// arrivals). Bounded spin: a capacity bug fails visibly instead of hanging.
__device__ __forceinline__ void gbar(unsigned* cnt, unsigned* gen, unsigned g) {
  __syncthreads();                 // block's stores drained (vmcnt(0) before s_barrier)
  if (threadIdx.x == 0) {
    __threadfence();               // agent-scope release: write back XCD L2
    if (atomicAdd(cnt, 1u) == g*(unsigned)NBLK - 1u) atomicAdd(gen, 1u);
    int guard = 0;
    while (__hip_atomic_load(gen, __ATOMIC_RELAXED, __HIP_MEMORY_SCOPE_AGENT) < g) {
      __builtin_amdgcn_s_sleep(8);
      if (++guard > (1 << 20)) break;
    }
    __threadfence();               // agent-scope acquire: invalidate local caches
  }
  __syncthreads();
}

// ---------------- Phase 0: convert x | transpose w1,w2 | build mask ----------------
__device__ __forceinline__ void prep_phase(
    const float* __restrict__ x, const int* __restrict__ adj,
    const float* __restrict__ w1, const float* __restrict__ w2,
    _Float16* __restrict__ xh, _Float16* __restrict__ w1T, _Float16* __restrict__ w2T,
    unsigned long long* __restrict__ bmg, SmemU& sm)
{
  const int b = blockIdx.x, t = threadIdx.x;
  if (b < 128) {                       // x -> f16, 512 float4/block
    #pragma unroll
    for (int j = 0; j < 2; ++j) {
      const int i = b*512 + j*256 + t;
      const float4 v = ((const float4*)x)[i];
      f16x4 o; o[0]=(_Float16)v.x; o[1]=(_Float16)v.y; o[2]=(_Float16)v.z; o[3]=(_Float16)v.w;
      ((f16x4*)xh)[i] = o;
    }
  } else if (b < 272) {                // weight transposes
    int ch, k0, K; const float* w; _Float16* wT;
    if (b < 144) { ch = b - 128; k0 = 0; K = 64; w = w1; wT = w1T; }
    else { const int u = b - 144; ch = u >> 3; k0 = (u & 7)*64; K = 512; w = w2; wT = w2T; }
    const float* src = w + ((size_t)ch*K + k0)*64;
    #pragma unroll
    for (int j = 0; j < 4; ++j) {
      const int u = t + j*256;
      const int k = u >> 4, seg = u & 15;
      const float4 v = ((const float4*)src)[(size_t)k*16 + seg];
      sm.tile[(seg*4+0)*72 + k] = (_Float16)v.x;
      sm.tile[(seg*4+1)*72 + k] = (_Float16)v.y;
      sm.tile[(seg*4+2)*72 + k] = (_Float16)v.z;
      sm.tile[(seg*4+3)*72 + k] = (_Float16)v.w;
    }
    __syncthreads();
    _Float16* dst = wT + (size_t)ch*64*K + k0;
    #pragma unroll
    for (int j = 0; j < 2; ++j) {
      const int u = t + j*256;
      const int f = u >> 3, seg = u & 7;
      const f16x8 o = *(const f16x8*)&sm.tile[f*72 + seg*8];
      *(f16x8*)(dst + (size_t)f*K + seg*8) = o;
    }
  } else {                             // adjacency -> 64-bit ballot mask
    const int wg = (b - 272)*4 + (t >> 6);
    const int lane = t & 63;
    for (int idx = wg; idx < BB*NN*16; idx += 960) {
      const int bb = idx >> 14;
      const int n = (idx >> 4) & (NN - 1);
      const int word = idx & 15;
      const int m = word*64 + lane;
      const int pred = (adj[((size_t)bb*NN + n)*NN + m] != 0) || (m == n);
      unsigned long long bits = __ballot(pred);
      if (lane == 0) bmg[idx] = bits;
    }
  }
}

// ---------------- Projection unit: 32 rows x 64 f via MFMA ----------------
template<int K>
__device__ __forceinline__ void proj_unit(
    int u, const _Float16* __restrict__ A, const _Float16* __restrict__ wT,
    const float* __restrict__ asrc, const float* __restrict__ adst,
    _Float16* __restrict__ HpT, float* __restrict__ s_out, float* __restrict__ d_out,
    SmemU& sm)
{
  const int bch = u & 31;
  const int row0 = (u >> 5) * 32;
  const int h = bch & 7; const int bc = bch >> 3; const int c = bc & 1;
  const int t = threadIdx.x;
  const int w = t >> 6, lane = t & 63;
  const int colr = lane & 15, quad = lane >> 4;

  const _Float16* Arow0 = A + ((size_t)bc*NN + row0 + colr)*K;
  const _Float16* Arow1 = Arow0 + (size_t)16*K;
  const _Float16* Brow  = wT + ((size_t)(c*HH + h)*64 + w*16 + colr)*K;

  f32x4 acc0 = {0.f,0.f,0.f,0.f}, acc1 = {0.f,0.f,0.f,0.f};
  #pragma unroll 4
  for (int kb = 0; kb < K; kb += 32) {
    const f16x8 a0 = *(const f16x8*)(Arow0 + kb + quad*8);
    const f16x8 a1 = *(const f16x8*)(Arow1 + kb + quad*8);
    const f16x8 bf = *(const f16x8*)(Brow  + kb + quad*8);
    acc0 = __builtin_amdgcn_mfma_f32_16x16x32_f16(a0, bf, acc0, 0, 0, 0);
    acc1 = __builtin_amdgcn_mfma_f32_16x16x32_f16(a1, bf, acc1, 0, 0, 0);
  }

  const float af  = asrc[(c*HH + h)*64 + w*16 + colr];
  const float bf_ = adst[(c*HH + h)*64 + w*16 + colr];
  _Float16* HT = HpT + ((size_t)bch*64 + w*16 + colr)*NN + row0;

  #pragma unroll
  for (int mt = 0; mt < 2; ++mt) {
    const f32x4 a = mt ? acc1 : acc0;
    f16x4 hv;
    #pragma unroll
    for (int i = 0; i < 4; ++i) {
      const float v = a[i];
      hv[i] = (_Float16)v;
      const float ex = __expf(2.f*v);
      const float th = 1.f - 2.f/(ex + 1.f);         // tanh(v)
      float ps = th * af, pd = th * bf_;
      #pragma unroll
      for (int off = 1; off < 16; off <<= 1) {
        ps += __shfl_xor(ps, off);
        pd += __shfl_xor(pd, off);
      }
      if (colr == 0) {
        sm.pr.sp[w][mt*16 + quad*4 + i] = ps;
        sm.pr.sd[w][mt*16 + quad*4 + i] = pd;
      }
    }
    *(f16x4*)(HT + mt*16 + quad*4) = hv;
  }
  __syncthreads();
  if (t < 32) {
    const float sv = sm.pr.sp[0][t] + sm.pr.sp[1][t] + sm.pr.sp[2][t] + sm.pr.sp[3][t];
    const float dv = sm.pr.sd[0][t] + sm.pr.sd[1][t] + sm.pr.sd[2][t] + sm.pr.sd[3][t];
    s_out[bch*NN + row0 + t] = sv * LOG2E;   // prescaled: exp(x) = exp2 of scaled domain
    d_out[bch*NN + row0 + t] = dv * LOG2E;
  }
  __syncthreads();   // WAR: sp/sd reused by the next proj_unit call
}

// ---------------- Fused attention: 64 rows (4 tiles of 16) per block, shared B/d stream ----
template<int LAYER>
__device__ __forceinline__ void attn_unit(
    const _Float16* __restrict__ HpT, const float* __restrict__ s_arr,
    const float* __restrict__ d_arr, const unsigned long long* __restrict__ bmg,
    _Float16* __restrict__ outp, SmemU& sm)
{
  const int bidx = blockIdx.x;
  const int bch = bidx & 31;               // bch%8 == blockIdx%8 -> XCD-local HpT
  const int row0 = (bidx >> 5) * 32;       // tiles: row0, +16, +512, +528
  const int bb = bch >> 4;                 // batch = bch/(CC*HH)
  const int t = threadIdx.x;
  const int w = t >> 6, lane = t & 63;
  const int colr = lane & 15, quad = lane >> 4;

  // wave-local maxd over d[bch]
  const float* dg = d_arr + (size_t)bch*NN;
  const float4* dg4 = (const float4*)dg;
  float mxl = -1e30f;
  #pragma unroll
  for (int j = 0; j < 4; ++j) {
    const float4 v = dg4[lane + 64*j];
    mxl = fmaxf(fmaxf(v.x, v.y), fmaxf(fmaxf(v.z, v.w), mxl));
  }
  #pragma unroll
  for (int off = 1; off < 64; off <<= 1) mxl = fmaxf(mxl, __shfl_xor(mxl, off));
  const float maxd = mxl;

  float sA[4], sB[4];
  const unsigned long long* bmp[4];
  #pragma unroll
  for (int rt = 0; rt < 4; ++rt) {
    const int r = row0 + (rt >> 1)*512 + (rt & 1)*16 + colr;
    const float s = s_arr[(size_t)bch*NN + r];
    const float so = s + maxd;
    const float offs = fmaxf(so, 0.2f*so);
    sA[rt] = s - offs;
    sB[rt] = 0.2f*s - offs;
    bmp[rt] = bmg + ((size_t)bb*NN + r)*16 + w*4;
  }

  const _Float16* Bp = HpT + (size_t)bch*64*NN + w*256 + quad*8;
  const float* dgk = dg + w*256 + quad*8;

  f32x4 acc[4][4], accs[4];
  #pragma unroll
  for (int rt = 0; rt < 4; ++rt) {
    accs[rt] = (f32x4){0.f,0.f,0.f,0.f};
    #pragma unroll
    for (int ft = 0; ft < 4; ++ft) acc[rt][ft] = (f32x4){0.f,0.f,0.f,0.f};
  }
  f16x8 ones;
  #pragma unroll
  for (int i = 0; i < 8; ++i) ones[i] = (_Float16)1.f;

  // prefetch ks=0
  f16x8 Bc[4];
  #pragma unroll
  for (int ft = 0; ft < 4; ++ft) Bc[ft] = *(const f16x8*)(Bp + (size_t)(ft*16 + colr)*NN);
  float4 dc0 = *(const float4*)(dgk);
  float4 dc1 = *(const float4*)(dgk + 4);
  unsigned long long mwc[4], mwn[4];
  #pragma unroll
  for (int rt = 0; rt < 4; ++rt) mwc[rt] = bmp[rt][0];

  #pragma unroll
  for (int ks = 0; ks < 8; ++ks) {
    f16x8 Bn[4]; float4 dn0, dn1;
    if (ks < 7) {
      #pragma unroll
      for (int ft = 0; ft < 4; ++ft)
        Bn[ft] = *(const f16x8*)(Bp + (size_t)(ft*16 + colr)*NN + (ks+1)*32);
      dn0 = *(const float4*)(dgk + (ks+1)*32);
      dn1 = *(const float4*)(dgk + (ks+1)*32 + 4);
    }
    if ((ks & 1) == 0 && ks < 6) {        // prefetch next mask word pair
      #pragma unroll
      for (int rt = 0; rt < 4; ++rt) mwn[rt] = bmp[rt][ks/2 + 1];
    }
    const float dd[8] = {dc0.x, dc0.y, dc0.z, dc0.w, dc1.x, dc1.y, dc1.z, dc1.w};
    union { f16x8 v; h16x2 h[4]; } Af[4];
    #pragma unroll
    for (int rt = 0; rt < 4; ++rt) {
      const unsigned mb = (unsigned)((mwc[rt] >> ((ks & 1)*32 + quad*8)) & 0xFFull);
      #pragma unroll
      for (int jp = 0; jp < 4; ++jp) {
        float pv[2];
        #pragma unroll
        for (int jj = 0; jj < 2; ++jj) {
          const int j = jp*2 + jj;
          const float dj = dd[j];
          const float l = fmaxf(sA[rt] + dj, fmaf(0.2f, dj, sB[rt]));  // scaled by log2e
          pv[jj] = ((mb >> j) & 1u) ? fexp2(l) : 0.f;
        }
        Af[rt].h[jp] = __builtin_amdgcn_cvt_pkrtz(pv[0], pv[1]);
      }
    }
    #pragma unroll
    for (int rt = 0; rt < 4; ++rt) {
      #pragma unroll
      for (int ft = 0; ft < 4; ++ft)
        acc[rt][ft] = __builtin_amdgcn_mfma_f32_16x16x32_f16(Af[rt].v, Bc[ft], acc[rt][ft], 0, 0, 0);
      accs[rt] = __builtin_amdgcn_mfma_f32_16x16x32_f16(Af[rt].v, ones, accs[rt], 0, 0, 0);
    }
    if (ks < 7) {
      #pragma unroll
      for (int ft = 0; ft < 4; ++ft) Bc[ft] = Bn[ft];
      dc0 = dn0; dc1 = dn1;
    }
    if ((ks & 1) && ks < 7) {
      #pragma unroll
      for (int rt = 0; rt < 4; ++rt) mwc[rt] = mwn[rt];
    }
  }

  // Epilogue in two halves (tiles 0-1, then 2-3) to keep LDS at 35.3 KB
  #pragma unroll
  for (int half = 0; half < 2; ++half) {
    if (half) __syncthreads();           // WAR vs previous half's reads
    if (colr == 0) {
      #pragma unroll
      for (int rt2 = 0; rt2 < 2; ++rt2)
        #pragma unroll
        for (int i = 0; i < 4; ++i)
          sm.at.dsP[w][rt2*16 + quad*4 + i] = accs[half*2 + rt2][i];
    }
    float* pw = sm.at.partials[w];
    #pragma unroll
    for (int rt2 = 0; rt2 < 2; ++rt2)
      #pragma unroll
      for (int ft = 0; ft < 4; ++ft)
        #pragma unroll
        for (int i = 0; i < 4; ++i)
          pw[(rt2*16 + quad*4 + i)*68 + ft*16 + colr] = acc[half*2 + rt2][ft][i];
    __syncthreads();

    const int r = t >> 3, f0 = (t & 7)*8;
    const float dsum = sm.at.dsP[0][r] + sm.at.dsP[1][r] + sm.at.dsP[2][r] + sm.at.dsP[3][r];
    const float inv = 1.f / dsum;
    float4 c0 = {0.f,0.f,0.f,0.f}, c1 = {0.f,0.f,0.f,0.f};
    #pragma unroll
    for (int w4 = 0; w4 < 4; ++w4) {
      const float* base = &sm.at.partials[w4][r*68 + f0];
      const float4 a0 = *(const float4*)base;
      const float4 a1 = *(const float4*)(base + 4);
      c0.x += a0.x; c0.y += a0.y; c0.z += a0.z; c0.w += a0.w;
      c1.x += a1.x; c1.y += a1.y; c1.z += a1.z; c1.w += a1.w;
    }
    const float cv[8] = {c0.x,c0.y,c0.z,c0.w, c1.x,c1.y,c1.z,c1.w};
    f16x8 o;
    #pragma unroll
    for (int i = 0; i < 8; ++i) {
      float v = cv[i] * inv;
      if (LAYER == 1) v = v > 0.f ? v : expm1f(v);
      o[i] = (_Float16)v;
    }
    const int rfull = half*32 + r;
    const int tile = rfull >> 4;
    const int grow = row0 + (tile >> 1)*512 + (tile & 1)*16 + (rfull & 15);
    const int bc = bch >> 3, h = bch & 7;
    if (LAYER == 1)
      *(f16x8*)(outp + ((size_t)bc*NN + grow)*512 + h*64 + f0) = o;
    else
      *(f16x8*)(outp + ((size_t)bch*NN + grow)*64 + f0) = o;
  }
}

// ---------------- Persistent mega-kernel ----------------
__global__ __launch_bounds__(256, 2) void gat_mega(
    const float* __restrict__ x, const int* __restrict__ adj,
    const float* __restrict__ w1, const float* __restrict__ as1, const float* __restrict__ ad1,
    const float* __restrict__ w2, const float* __restrict__ as2, const float* __restrict__ ad2,
    _Float16* __restrict__ xh, _Float16* __restrict__ w1T, _Float16* __restrict__ w2T,
    unsigned long long* __restrict__ bmg, _Float16* __restrict__ HpT, _Float16* __restrict__ XB,
    float* __restrict__ s_v, float* __restrict__ d_v, float* __restrict__ out,
    unsigned* cnt, unsigned* gen)
{
  __shared__ SmemU sm;

  prep_phase(x, adj, w1, w2, xh, w1T, w2T, bmg, sm);
  gbar(cnt, gen, 1u);

  proj_unit<64>(blockIdx.x,        xh, w1T, as1, ad1, HpT, s_v, d_v, sm);
  proj_unit<64>(blockIdx.x + NBLK, xh, w1T, as1, ad1, HpT, s_v, d_v, sm);
  gbar(cnt, gen, 2u);

  attn_unit<1>(HpT, s_v, d_v, bmg, XB, sm);
  gbar(cnt, gen, 3u);

  proj_unit<512>(blockIdx.x,        XB, w2T, as2, ad2, HpT, s_v, d_v, sm);
  proj_unit<512>(blockIdx.x + NBLK, XB, w2T, as2, ad2, HpT, s_v, d_v, sm);
  gbar(cnt, gen, 4u);

  attn_unit<2>(HpT, s_v, d_v, bmg, XB, sm);
  gbar(cnt, gen, 5u);

  // mean over heads
  #pragma unroll
  for (int j = 0; j < 2; ++j) {
    const int o = (blockIdx.x + j*NBLK)*256 + threadIdx.x;
    const int f = o & 63;
    const int n = (o >> 6) & (NN - 1);
    const int bc = o >> 16;
    float acc = 0.f;
    #pragma unroll
    for (int h = 0; h < HH; ++h)
      acc += (float)XB[(((size_t)bc*HH + h)*NN + n)*64 + f];
    out[o] = acc * 0.125f;
  }
}

extern "C" void kernel_launch(void* const* d_in, const int* in_sizes, int n_in,
                              void* d_out, int out_size, void* d_ws, size_t ws_size,
                              hipStream_t stream)
{
  const float* x   = (const float*)d_in[0];
  const int*   adj = (const int*)d_in[1];
  const float* w1  = (const float*)d_in[2];
  const float* as1 = (const float*)d_in[3];
  const float* ad1 = (const float*)d_in[4];
  const float* w2  = (const float*)d_in[5];
  const float* as2 = (const float*)d_in[6];
  const float* ad2 = (const float*)d_in[7];

  char* w8 = (char*)d_ws;
  _Float16* HpT = (_Float16*)(w8);                          // 4 MB  [bch][64][N]
  _Float16* XB  = (_Float16*)(w8 + (4u<<20));               // 4 MB  x1 [bc][N][512] then out2 [bch][N][64]
  _Float16* xh  = (_Float16*)(w8 + (8u<<20));               // 512 KB
  _Float16* w1T = (_Float16*)(w8 + (8u<<20) + (512u<<10));  // 128 KB
  _Float16* w2T = (_Float16*)(w8 + (8u<<20) + (768u<<10));  // 1 MB
  float* s_v = (float*)(w8 + (10u<<20));                    // 128 KB (prescaled by log2e)
  float* d_v = (float*)(w8 + (10u<<20) + SVN*4);            // 128 KB
  unsigned long long* bmg = (unsigned long long*)(w8 + (10u<<20) + SVN*8);  // 256 KB
  unsigned* bar = (unsigned*)(w8 + (10u<<20) + SVN*8 + (256u<<10));         // 16 B

  hipMemsetAsync(bar, 0, 16, stream);     // zero barrier counter+generation
  gat_mega<<<NBLK, 256, 0, stream>>>(x, adj, w1, as1, ad1, w2, as2, ad2,
                                     xh, w1T, w2T, bmg, HpT, XB, s_v, d_v,
                                     (float*)d_out, bar, bar + 1);
}

// Round 2
// 178.511 us; speedup vs baseline: 2.0911x; 2.0911x over previous
//
#include <hip/hip_runtime.h>
#include <hip/hip_bf16.h>

#define BB 2
#define CC 2
#define NN 1024
#define F0V 64
#define HH 8
#define FFV 64
#define BCHN (BB*CC*HH)          // 32
#define SVN  (BB*CC*HH*NN)       // 32768
#define LOG2E 1.44269504f

typedef _Float16 f16x8 __attribute__((ext_vector_type(8)));
typedef _Float16 f16x4 __attribute__((ext_vector_type(4)));
typedef __fp16 h16x2 __attribute__((ext_vector_type(2)));   // cvt_pkrtz native type
typedef float f32x4 __attribute__((ext_vector_type(4)));

__device__ __forceinline__ float fexp2(float x) {
  float r; asm("v_exp_f32 %0, %1" : "=v"(r) : "v"(x)); return r;
}

// ---------------- Fused prep: convert_x | transpose w1 | transpose w2 | build_mask ----------------
__global__ __launch_bounds__(256) void prep_kernel(
    const float* __restrict__ x, const int* __restrict__ adj,
    const float* __restrict__ w1, const float* __restrict__ w2,
    _Float16* __restrict__ xh, _Float16* __restrict__ w1T, _Float16* __restrict__ w2T,
    unsigned long long* __restrict__ bmg)
{
  __shared__ __align__(16) _Float16 tile[64*72];
  const int bx = blockIdx.x;
  const int t = threadIdx.x;
  if (bx < 256) {
    const int i = bx*256 + t;
    const float4 v = ((const float4*)x)[i];
    f16x4 o; o[0]=(_Float16)v.x; o[1]=(_Float16)v.y; o[2]=(_Float16)v.z; o[3]=(_Float16)v.w;
    ((f16x4*)xh)[i] = o;
  } else if (bx < 400) {
    int ch, k0, K; const float* w; _Float16* wT;
    if (bx < 272) { ch = bx - 256; k0 = 0; K = 64; w = w1; wT = w1T; }
    else { const int u = bx - 272; ch = u >> 3; k0 = (u & 7)*64; K = 512; w = w2; wT = w2T; }
    const float* src = w + ((size_t)ch*K + k0)*64;
    #pragma unroll
    for (int j = 0; j < 4; ++j) {
      const int u = t + j*256;
      const int k = u >> 4, seg = u & 15;
      const float4 v = ((const float4*)src)[(size_t)k*16 + seg];
      tile[(seg*4+0)*72 + k] = (_Float16)v.x;
      tile[(seg*4+1)*72 + k] = (_Float16)v.y;
      tile[(seg*4+2)*72 + k] = (_Float16)v.z;
      tile[(seg*4+3)*72 + k] = (_Float16)v.w;
    }
    __syncthreads();
    _Float16* dst = wT + (size_t)ch*64*K + k0;
    #pragma unroll
    for (int j = 0; j < 2; ++j) {
      const int u = t + j*256;
      const int f = u >> 3, seg = u & 7;
      const f16x8 o = *(const f16x8*)&tile[f*72 + seg*8];
      *(f16x8*)(dst + (size_t)f*K + seg*8) = o;
    }
  } else {
    const int wg = (bx - 400)*4 + (t >> 6);
    const int lane = t & 63;
    for (int idx = wg; idx < BB*NN*16; idx += 1024) {
      const int b = idx >> 14;
      const int n = (idx >> 4) & (NN - 1);
      const int word = idx & 15;
      const int m = word*64 + lane;
      const int pred = (adj[((size_t)b*NN + n)*NN + m] != 0) || (m == n);
      unsigned long long bits = __ballot(pred);
      if (lane == 0) bmg[idx] = bits;
    }
  }
}

// ---------------- Projection via MFMA: C[32 rows][64 f] = A[rows][K] @ wT[f][K]^T ----------------
template<int K>
__global__ __launch_bounds__(256) void proj_mfma(
    const _Float16* __restrict__ A,      // [bc][N][K]
    const _Float16* __restrict__ wT,     // [c*HH+h][64][K]
    const float* __restrict__ asrc, const float* __restrict__ adst,
    _Float16* __restrict__ HpT, float* __restrict__ s_out, float* __restrict__ d_out)
{
  __shared__ float sp[4][32], sd[4][32];
  const int bch = blockIdx.y;
  const int h = bch % HH; const int bc = bch / HH; const int c = bc % CC;
  const int row0 = blockIdx.x*32;
  const int t = threadIdx.x;
  const int w = t >> 6, lane = t & 63;
  const int colr = lane & 15, quad = lane >> 4;

  const _Float16* Arow0 = A + ((size_t)bc*NN + row0 + colr)*K;
  const _Float16* Arow1 = Arow0 + (size_t)16*K;
  const _Float16* Brow  = wT + ((size_t)(c*HH + h)*64 + w*16 + colr)*K;

  f32x4 acc0 = {0.f,0.f,0.f,0.f}, acc1 = {0.f,0.f,0.f,0.f};
  #pragma unroll 4
  for (int kb = 0; kb < K; kb += 32) {
    const f16x8 a0 = *(const f16x8*)(Arow0 + kb + quad*8);
    const f16x8 a1 = *(const f16x8*)(Arow1 + kb + quad*8);
    const f16x8 bf = *(const f16x8*)(Brow  + kb + quad*8);
    acc0 = __builtin_amdgcn_mfma_f32_16x16x32_f16(a0, bf, acc0, 0, 0, 0);
    acc1 = __builtin_amdgcn_mfma_f32_16x16x32_f16(a1, bf, acc1, 0, 0, 0);
  }

  const float af = asrc[(c*HH + h)*64 + w*16 + colr];
  const float bf_ = adst[(c*HH + h)*64 + w*16 + colr];
  _Float16* HT = HpT + ((size_t)bch*64 + w*16 + colr)*NN + row0;

  #pragma unroll
  for (int mt = 0; mt < 2; ++mt) {
    const f32x4 a = mt ? acc1 : acc0;
    f16x4 hv;
    #pragma unroll
    for (int i = 0; i < 4; ++i) {
      const float v = a[i];
      hv[i] = (_Float16)v;
      const float ex = __expf(2.f*v);
      const float th = 1.f - 2.f/(ex + 1.f);         // tanh(v)
      float ps = th * af, pd = th * bf_;
      #pragma unroll
      for (int off = 1; off < 16; off <<= 1) {
        ps += __shfl_xor(ps, off);
        pd += __shfl_xor(pd, off);
      }
      if (colr == 0) {
        sp[w][mt*16 + quad*4 + i] = ps;
        sd[w][mt*16 + quad*4 + i] = pd;
      }
    }
    *(f16x4*)(HT + mt*16 + quad*4) = hv;
  }
  __syncthreads();
  if (t < 32) {
    const float sv = sp[0][t] + sp[1][t] + sp[2][t] + sp[3][t];
    const float dv = sd[0][t] + sd[1][t] + sd[2][t] + sd[3][t];
    // pre-scale by log2(e): attention inner loop uses raw v_exp_f32 (2^x),
    // saving one v_mul per score (67M scores). max/linear ops commute with
    // the positive scaling, so offsets/softmax are unchanged.
    s_out[bch*NN + row0 + t] = sv * LOG2E;
    d_out[bch*NN + row0 + t] = dv * LOG2E;
  }
}

// ---------------- Fused attention v4: 32-row blocks, XCD-swizzled grid, register P ----------
// grid (x=bch=32, y=N/32=32) -> linear%8 = bch%8 = XCD; HpT slice stays L2-local.
// 256 thr; wave w owns k-quarter [w*256,+256). Lane: rows colr & colr+16, k = quad*8 within 32-k step.
// dsum via ones-B MFMA; B/d prefetch depth 1; LDS only for the final cross-wave reduction.
template<int LAYER>
__global__ __launch_bounds__(256, 4) void attn_mfma(
    const _Float16* __restrict__ HpT, const float* __restrict__ s_arr,
    const float* __restrict__ d_arr, const unsigned long long* __restrict__ bmg,
    _Float16* __restrict__ outp)
{
  __shared__ float partials[4][32*68];   // 34.8 KB, stride 68 (2-way bank alias = free)
  __shared__ float dsP[4][32];
  const int bch = blockIdx.x;
  const int b = bch / (CC*HH);
  const int row0 = blockIdx.y*32;
  const int t = threadIdx.x;
  const int w = t >> 6, lane = t & 63;
  const int colr = lane & 15, quad = lane >> 4;

  // wave-local maxd over d[bch] (no barrier)
  const float* dg = d_arr + (size_t)bch*NN;
  const float4* dg4 = (const float4*)dg;
  float mxl = -1e30f;
  #pragma unroll
  for (int j = 0; j < 4; ++j) {
    const float4 v = dg4[lane + 64*j];
    mxl = fmaxf(fmaxf(v.x, v.y), fmaxf(fmaxf(v.z, v.w), mxl));
  }
  #pragma unroll
  for (int off = 1; off < 64; off <<= 1) mxl = fmaxf(mxl, __shfl_xor(mxl, off));
  const float maxd = mxl;

  const int r0 = row0 + colr, r1 = r0 + 16;
  const float s0 = s_arr[(size_t)bch*NN + r0];
  const float s1 = s_arr[(size_t)bch*NN + r1];
  const float so0 = s0 + maxd, so1 = s1 + maxd;
  const float offs0 = fmaxf(so0, 0.2f*so0);   // >= lrelu(s0+d) for all d
  const float offs1 = fmaxf(so1, 0.2f*so1);
  // folded lrelu-minus-offset: l-offs = max(sA + d, fma(0.2, d, sB))
  const float sA0 = s0 - offs0, sB0 = 0.2f*s0 - offs0;
  const float sA1 = s1 - offs1, sB1 = 0.2f*s1 - offs1;

  unsigned long long m0[4], m1[4];
  {
    const unsigned long long* bm0 = bmg + ((size_t)b*NN + r0)*16 + w*4;
    const unsigned long long* bm1 = bmg + ((size_t)b*NN + r1)*16 + w*4;
    #pragma unroll
    for (int j = 0; j < 4; ++j) { m0[j] = bm0[j]; m1[j] = bm1[j]; }
  }

  const _Float16* Bg = HpT + (size_t)bch*64*NN;
  const int kbase = w*256;
  const _Float16* Bp = Bg + kbase + quad*8;

  f32x4 acc[2][4], accs[2];
  #pragma unroll
  for (int rt = 0; rt < 2; ++rt) {
    accs[rt] = (f32x4){0.f,0.f,0.f,0.f};
    #pragma unroll
    for (int ft = 0; ft < 4; ++ft) acc[rt][ft] = (f32x4){0.f,0.f,0.f,0.f};
  }
  f16x8 ones;
  #pragma unroll
  for (int i = 0; i < 8; ++i) ones[i] = (_Float16)1.f;

  // prefetch ks=0
  f16x8 Bc[4];
  #pragma unroll
  for (int ft = 0; ft < 4; ++ft) Bc[ft] = *(const f16x8*)(Bp + (size_t)(ft*16 + colr)*NN);
  float4 dc0 = *(const float4*)(dg + kbase + quad*8);
  float4 dc1 = *(const float4*)(dg + kbase + quad*8 + 4);

  #pragma unroll
  for (int ks = 0; ks < 8; ++ks) {
    f16x8 Bn[4]; float4 dn0, dn1;
    if (ks < 7) {
      #pragma unroll
      for (int ft = 0; ft < 4; ++ft)
        Bn[ft] = *(const f16x8*)(Bp + (size_t)(ft*16 + colr)*NN + (ks+1)*32);
      dn0 = *(const float4*)(dg + kbase + (ks+1)*32 + quad*8);
      dn1 = *(const float4*)(dg + kbase + (ks+1)*32 + quad*8 + 4);
    }
    const unsigned mb0 = (unsigned)((m0[ks >> 1] >> ((ks & 1)*32 + quad*8)) & 0xFFull);
    const unsigned mb1 = (unsigned)((m1[ks >> 1] >> ((ks & 1)*32 + quad*8)) & 0xFFull);
    const float dd[8] = {dc0.x, dc0.y, dc0.z, dc0.w, dc1.x, dc1.y, dc1.z, dc1.w};
    union { f16x8 v; h16x2 h[4]; } A0, A1;
    #pragma unroll
    for (int jp = 0; jp < 4; ++jp) {
      float p0[2], p1[2];
      #pragma unroll
      for (int jj = 0; jj < 2; ++jj) {
        const int j = jp*2 + jj;
        const float dj = dd[j];
        const float l0 = fmaxf(sA0 + dj, fmaf(0.2f, dj, sB0));  // log2e-scaled domain
        const float l1 = fmaxf(sA1 + dj, fmaf(0.2f, dj, sB1));
        p0[jj] = ((mb0 >> j) & 1u) ? fexp2(l0) : 0.f;
        p1[jj] = ((mb1 >> j) & 1u) ? fexp2(l1) : 0.f;
      }
      A0.h[jp] = __builtin_amdgcn_cvt_pkrtz(p0[0], p0[1]);
      A1.h[jp] = __builtin_amdgcn_cvt_pkrtz(p1[0], p1[1]);
    }
    #pragma unroll
    for (int ft = 0; ft < 4; ++ft) {
      acc[0][ft] = __builtin_amdgcn_mfma_f32_16x16x32_f16(A0.v, Bc[ft], acc[0][ft], 0, 0, 0);
      acc[1][ft] = __builtin_amdgcn_mfma_f32_16x16x32_f16(A1.v, Bc[ft], acc[1][ft], 0, 0, 0);
    }
    accs[0] = __builtin_amdgcn_mfma_f32_16x16x32_f16(A0.v, ones, accs[0], 0, 0, 0);
    accs[1] = __builtin_amdgcn_mfma_f32_16x16x32_f16(A1.v, ones, accs[1], 0, 0, 0);
    if (ks < 7) {
      #pragma unroll
      for (int ft = 0; ft < 4; ++ft) Bc[ft] = Bn[ft];
      dc0 = dn0; dc1 = dn1;
    }
  }

  // accs[rt][i] = this-quarter row-sum for row rt*16 + quad*4 + i (same across colr)
  if (colr == 0) {
    #pragma unroll
    for (int i = 0; i < 4; ++i) {
      dsP[w][quad*4 + i] = accs[0][i];
      dsP[w][16 + quad*4 + i] = accs[1][i];
    }
  }
  float* pw = partials[w];
  #pragma unroll
  for (int rt = 0; rt < 2; ++rt)
    #pragma unroll
    for (int ft = 0; ft < 4; ++ft)
      #pragma unroll
      for (int i = 0; i < 4; ++i)
        pw[(rt*16 + quad*4 + i)*68 + ft*16 + colr] = acc[rt][ft][i];
  __syncthreads();

  // final: thread t -> row r = t>>3, features f0 = (t&7)*8
  const int r = t >> 3, f0 = (t & 7)*8;
  const float dsum = dsP[0][r] + dsP[1][r] + dsP[2][r] + dsP[3][r];
  const float inv = 1.f / dsum;
  float4 c0 = {0.f,0.f,0.f,0.f}, c1 = {0.f,0.f,0.f,0.f};
  #pragma unroll
  for (int w4 = 0; w4 < 4; ++w4) {
    const float* base = &partials[w4][r*68 + f0];
    const float4 a0 = *(const float4*)base;
    const float4 a1 = *(const float4*)(base + 4);
    c0.x += a0.x; c0.y += a0.y; c0.z += a0.z; c0.w += a0.w;
    c1.x += a1.x; c1.y += a1.y; c1.z += a1.z; c1.w += a1.w;
  }
  const float cv[8] = {c0.x,c0.y,c0.z,c0.w, c1.x,c1.y,c1.z,c1.w};
  f16x8 o;
  #pragma unroll
  for (int i = 0; i < 8; ++i) {
    float v = cv[i] * inv;
    if (LAYER == 1) v = v > 0.f ? v : expm1f(v);
    o[i] = (_Float16)v;
  }
  const int bc = bch / HH, h = bch % HH;
  if (LAYER == 1)
    *(f16x8*)(outp + ((size_t)bc*NN + row0 + r)*512 + h*64 + f0) = o;
  else
    *(f16x8*)(outp + ((size_t)bch*NN + row0 + r)*64 + f0) = o;
}

// ---------------- Mean over heads (f16 in) -> fp32 out ----------------
__global__ __launch_bounds__(256) void reduce_heads(
    const _Float16* __restrict__ out2, float* __restrict__ out)
{
  const int o = blockIdx.x*256 + threadIdx.x;
  const int f = o & 63;
  const int n = (o >> 6) & (NN - 1);
  const int bc = o >> 16;
  float acc = 0.f;
  #pragma unroll
  for (int h = 0; h < HH; ++h)
    acc += (float)out2[(((size_t)bc*HH + h)*NN + n)*FFV + f];
  out[o] = acc * 0.125f;
}

extern "C" void kernel_launch(void* const* d_in, const int* in_sizes, int n_in,
                              void* d_out, int out_size, void* d_ws, size_t ws_size,
                              hipStream_t stream)
{
  const float* x   = (const float*)d_in[0];
  const int*   adj = (const int*)d_in[1];
  const float* w1  = (const float*)d_in[2];
  const float* as1 = (const float*)d_in[3];
  const float* ad1 = (const float*)d_in[4];
  const float* w2  = (const float*)d_in[5];
  const float* as2 = (const float*)d_in[6];
  const float* ad2 = (const float*)d_in[7];

  char* w8 = (char*)d_ws;
  _Float16* HpT = (_Float16*)(w8);                         // 4 MB  [bch][64][N]
  _Float16* XB  = (_Float16*)(w8 + (4u<<20));              // 4 MB  x1 [bc][N][512] then out2 [bch][N][64]
  _Float16* xh  = (_Float16*)(w8 + (8u<<20));              // 512 KB [bc][N][64]
  _Float16* w1T = (_Float16*)(w8 + (8u<<20) + (512u<<10)); // 128 KB [ch][64][64]
  _Float16* w2T = (_Float16*)(w8 + (8u<<20) + (768u<<10)); // 1 MB   [ch][64][512]
  float* s_v = (float*)(w8 + (10u<<20));                   // 128 KB (log2e-scaled)
  float* d_v = (float*)(w8 + (10u<<20) + SVN*4);           // 128 KB (log2e-scaled)
  unsigned long long* bmg = (unsigned long long*)(w8 + (10u<<20) + SVN*8);  // 256 KB

  prep_kernel<<<656, 256, 0, stream>>>(x, adj, w1, w2, xh, w1T, w2T, bmg);
  proj_mfma<64><<<dim3(NN/32, BCHN), 256, 0, stream>>>(xh, w1T, as1, ad1, HpT, s_v, d_v);
  attn_mfma<1><<<dim3(BCHN, NN/32), 256, 0, stream>>>(HpT, s_v, d_v, bmg, XB);
  proj_mfma<512><<<dim3(NN/32, BCHN), 256, 0, stream>>>(XB, w2T, as2, ad2, HpT, s_v, d_v);
  attn_mfma<2><<<dim3(BCHN, NN/32), 256, 0, stream>>>(HpT, s_v, d_v, bmg, XB);
  reduce_heads<<<dim3((unsigned)(out_size/256)), 256, 0, stream>>>(XB, (float*)d_out);
}

// Round 3
// 169.475 us; speedup vs baseline: 2.2026x; 1.0533x over previous
//
#include <hip/hip_runtime.h>

#define BB 2
#define CC 2
#define NN 1024
#define HH 8
#define FFV 64
#define BCHN (BB*CC*HH)          // 32
#define SVN  (BB*CC*HH*NN)       // 32768
#define LOG2E 1.44269504f

typedef _Float16 f16x8 __attribute__((ext_vector_type(8)));
typedef _Float16 f16x4 __attribute__((ext_vector_type(4)));
typedef __fp16 h16x2 __attribute__((ext_vector_type(2)));   // cvt_pkrtz native type
typedef float f32x4 __attribute__((ext_vector_type(4)));

__device__ __forceinline__ float fexp2(float x) {
  float r; asm("v_exp_f32 %0, %1" : "=v"(r) : "v"(x)); return r;
}

// ---------------- Fused layer-1 projection + prep (one dispatch, no intra-deps) ----------
// bx <  1024 : proj1 (reads x f32 + w1 f32 directly; writes HpT, s_v, d_v)
// bx <  1152 : w2 transpose -> w2T (f16)   [consumed by proj2, 2 dispatches later]
// bx >= 1152 : adjacency -> 64-bit ballot mask, 8-deep batched loads [consumed by attn1]
__global__ __launch_bounds__(256) void proj1_fused(
    const float* __restrict__ x, const int* __restrict__ adj,
    const float* __restrict__ w1, const float* __restrict__ w2,
    const float* __restrict__ asrc, const float* __restrict__ adst,
    _Float16* __restrict__ w2T, unsigned long long* __restrict__ bmg,
    _Float16* __restrict__ HpT, float* __restrict__ s_out, float* __restrict__ d_out)
{
  __shared__ union {
    __align__(16) _Float16 tile[64*72];                 // transpose staging (aux)
    struct { float sp[4][32]; float sd[4][32]; } pr;    // proj reductions
  } sm;
  const int bx = blockIdx.x;
  const int t = threadIdx.x;
  const int w = t >> 6, lane = t & 63;
  const int colr = lane & 15, quad = lane >> 4;

  if (bx < 1024) {
    // ---- projection: C[32 rows][64 f] = x[rows][64] @ w1[c,h][64k][64f] ----
    const int bch = bx & 31;
    const int row0 = (bx >> 5) * 32;
    const int h = bch & 7; const int bc = bch >> 3; const int c = bc & 1;

    const float* Ar0 = x + ((size_t)bc*NN + row0 + colr)*64;
    const float* Ar1 = Ar0 + (size_t)16*64;
    const float* Bw  = w1 + ((size_t)(c*HH + h))*64*64 + w*16 + colr;  // column f, stride 64

    f32x4 acc0 = {0.f,0.f,0.f,0.f}, acc1 = {0.f,0.f,0.f,0.f};
    #pragma unroll
    for (int kb = 0; kb < 64; kb += 32) {
      const float4 pa0 = *(const float4*)(Ar0 + kb + quad*8);
      const float4 pa1 = *(const float4*)(Ar0 + kb + quad*8 + 4);
      const float4 pb0 = *(const float4*)(Ar1 + kb + quad*8);
      const float4 pb1 = *(const float4*)(Ar1 + kb + quad*8 + 4);
      float bv[8];
      #pragma unroll
      for (int j = 0; j < 8; ++j) bv[j] = Bw[(size_t)(kb + quad*8 + j)*64];
      f16x8 a0, a1, bf;
      a0[0]=(_Float16)pa0.x; a0[1]=(_Float16)pa0.y; a0[2]=(_Float16)pa0.z; a0[3]=(_Float16)pa0.w;
      a0[4]=(_Float16)pa1.x; a0[5]=(_Float16)pa1.y; a0[6]=(_Float16)pa1.z; a0[7]=(_Float16)pa1.w;
      a1[0]=(_Float16)pb0.x; a1[1]=(_Float16)pb0.y; a1[2]=(_Float16)pb0.z; a1[3]=(_Float16)pb0.w;
      a1[4]=(_Float16)pb1.x; a1[5]=(_Float16)pb1.y; a1[6]=(_Float16)pb1.z; a1[7]=(_Float16)pb1.w;
      #pragma unroll
      for (int j = 0; j < 8; ++j) bf[j] = (_Float16)bv[j];
      acc0 = __builtin_amdgcn_mfma_f32_16x16x32_f16(a0, bf, acc0, 0, 0, 0);
      acc1 = __builtin_amdgcn_mfma_f32_16x16x32_f16(a1, bf, acc1, 0, 0, 0);
    }

    const float af  = asrc[(c*HH + h)*64 + w*16 + colr];
    const float bf_ = adst[(c*HH + h)*64 + w*16 + colr];
    _Float16* HT = HpT + ((size_t)bch*64 + w*16 + colr)*NN + row0;

    #pragma unroll
    for (int mt = 0; mt < 2; ++mt) {
      const f32x4 a = mt ? acc1 : acc0;
      f16x4 hv;
      #pragma unroll
      for (int i = 0; i < 4; ++i) {
        const float v = a[i];
        hv[i] = (_Float16)v;
        const float ex = __expf(2.f*v);
        const float th = 1.f - 2.f/(ex + 1.f);         // tanh(v)
        float ps = th * af, pd = th * bf_;
        #pragma unroll
        for (int off = 1; off < 16; off <<= 1) {
          ps += __shfl_xor(ps, off);
          pd += __shfl_xor(pd, off);
        }
        if (colr == 0) {
          sm.pr.sp[w][mt*16 + quad*4 + i] = ps;
          sm.pr.sd[w][mt*16 + quad*4 + i] = pd;
        }
      }
      *(f16x4*)(HT + mt*16 + quad*4) = hv;
    }
    __syncthreads();
    if (t < 32) {
      const float sv = sm.pr.sp[0][t] + sm.pr.sp[1][t] + sm.pr.sp[2][t] + sm.pr.sp[3][t];
      const float dv = sm.pr.sd[0][t] + sm.pr.sd[1][t] + sm.pr.sd[2][t] + sm.pr.sd[3][t];
      // prescaled by log2(e): attention uses raw v_exp_f32 (2^x) on this domain
      s_out[bch*NN + row0 + t] = sv * LOG2E;
      d_out[bch*NN + row0 + t] = dv * LOG2E;
    }
  } else if (bx < 1152) {
    // ---- w2 transpose -> w2T[ch][64 f][512 k] ----
    const int u = bx - 1024;
    const int ch = u >> 3, k0 = (u & 7)*64;
    const float* src = w2 + ((size_t)ch*512 + k0)*64;
    #pragma unroll
    for (int j = 0; j < 4; ++j) {
      const int uu = t + j*256;
      const int k = uu >> 4, seg = uu & 15;
      const float4 v = ((const float4*)src)[(size_t)k*16 + seg];
      sm.tile[(seg*4+0)*72 + k] = (_Float16)v.x;
      sm.tile[(seg*4+1)*72 + k] = (_Float16)v.y;
      sm.tile[(seg*4+2)*72 + k] = (_Float16)v.z;
      sm.tile[(seg*4+3)*72 + k] = (_Float16)v.w;
    }
    __syncthreads();
    _Float16* dst = w2T + (size_t)ch*64*512 + k0;
    #pragma unroll
    for (int j = 0; j < 2; ++j) {
      const int uu = t + j*256;
      const int f = uu >> 3, seg = uu & 7;
      const f16x8 o = *(const f16x8*)&sm.tile[f*72 + seg*8];
      *(f16x8*)(dst + (size_t)f*512 + seg*8) = o;
    }
  } else {
    // ---- mask build: 256 blocks x 4 waves x 32 words; 8 independent loads per batch ----
    const int g = (bx - 1152)*4 + w;     // 1024 wave-units
    const int base = g*32;
    #pragma unroll
    for (int jb = 0; jb < 4; ++jb) {
      int vals[8];
      #pragma unroll
      for (int i = 0; i < 8; ++i) {
        const int idx = base + jb*8 + i;
        const int b = idx >> 14;
        const int n = (idx >> 4) & (NN - 1);
        const int wd = idx & 15;
        vals[i] = adj[((size_t)b*NN + n)*NN + wd*64 + lane];
      }
      #pragma unroll
      for (int i = 0; i < 8; ++i) {
        const int idx = base + jb*8 + i;
        const int n = (idx >> 4) & (NN - 1);
        const int m = (idx & 15)*64 + lane;
        const unsigned long long bits = __ballot((vals[i] != 0) || (m == n));
        if (lane == 0) bmg[idx] = bits;
      }
    }
  }
}

// ---------------- Projection via MFMA (layer 2): C[32 rows][64 f] = A[rows][512] @ w2T^T ----
template<int K>
__global__ __launch_bounds__(256) void proj_mfma(
    const _Float16* __restrict__ A,      // [bc][N][K]
    const _Float16* __restrict__ wT,     // [c*HH+h][64][K]
    const float* __restrict__ asrc, const float* __restrict__ adst,
    _Float16* __restrict__ HpT, float* __restrict__ s_out, float* __restrict__ d_out)
{
  __shared__ float sp[4][32], sd[4][32];
  const int bch = blockIdx.y;
  const int h = bch % HH; const int bc = bch / HH; const int c = bc % CC;
  const int row0 = blockIdx.x*32;
  const int t = threadIdx.x;
  const int w = t >> 6, lane = t & 63;
  const int colr = lane & 15, quad = lane >> 4;

  const _Float16* Arow0 = A + ((size_t)bc*NN + row0 + colr)*K;
  const _Float16* Arow1 = Arow0 + (size_t)16*K;
  const _Float16* Brow  = wT + ((size_t)(c*HH + h)*64 + w*16 + colr)*K;

  f32x4 acc0 = {0.f,0.f,0.f,0.f}, acc1 = {0.f,0.f,0.f,0.f};
  #pragma unroll 4
  for (int kb = 0; kb < K; kb += 32) {
    const f16x8 a0 = *(const f16x8*)(Arow0 + kb + quad*8);
    const f16x8 a1 = *(const f16x8*)(Arow1 + kb + quad*8);
    const f16x8 bf = *(const f16x8*)(Brow  + kb + quad*8);
    acc0 = __builtin_amdgcn_mfma_f32_16x16x32_f16(a0, bf, acc0, 0, 0, 0);
    acc1 = __builtin_amdgcn_mfma_f32_16x16x32_f16(a1, bf, acc1, 0, 0, 0);
  }

  const float af = asrc[(c*HH + h)*64 + w*16 + colr];
  const float bf_ = adst[(c*HH + h)*64 + w*16 + colr];
  _Float16* HT = HpT + ((size_t)bch*64 + w*16 + colr)*NN + row0;

  #pragma unroll
  for (int mt = 0; mt < 2; ++mt) {
    const f32x4 a = mt ? acc1 : acc0;
    f16x4 hv;
    #pragma unroll
    for (int i = 0; i < 4; ++i) {
      const float v = a[i];
      hv[i] = (_Float16)v;
      const float ex = __expf(2.f*v);
      const float th = 1.f - 2.f/(ex + 1.f);         // tanh(v)
      float ps = th * af, pd = th * bf_;
      #pragma unroll
      for (int off = 1; off < 16; off <<= 1) {
        ps += __shfl_xor(ps, off);
        pd += __shfl_xor(pd, off);
      }
      if (colr == 0) {
        sp[w][mt*16 + quad*4 + i] = ps;
        sd[w][mt*16 + quad*4 + i] = pd;
      }
    }
    *(f16x4*)(HT + mt*16 + quad*4) = hv;
  }
  __syncthreads();
  if (t < 32) {
    const float sv = sp[0][t] + sp[1][t] + sp[2][t] + sp[3][t];
    const float dv = sd[0][t] + sd[1][t] + sd[2][t] + sd[3][t];
    s_out[bch*NN + row0 + t] = sv * LOG2E;
    d_out[bch*NN + row0 + t] = dv * LOG2E;
  }
}

// ---------------- Fused attention: 32-row blocks, XCD-swizzled grid, register P ----------
template<int LAYER>
__global__ __launch_bounds__(256, 4) void attn_mfma(
    const _Float16* __restrict__ HpT, const float* __restrict__ s_arr,
    const float* __restrict__ d_arr, const unsigned long long* __restrict__ bmg,
    _Float16* __restrict__ outp)
{
  __shared__ float partials[4][32*68];   // 34.8 KB, stride 68 (2-way bank alias = free)
  __shared__ float dsP[4][32];
  const int bch = blockIdx.x;
  const int b = bch / (CC*HH);
  const int row0 = blockIdx.y*32;
  const int t = threadIdx.x;
  const int w = t >> 6, lane = t & 63;
  const int colr = lane & 15, quad = lane >> 4;

  // wave-local maxd over d[bch] (no barrier)
  const float* dg = d_arr + (size_t)bch*NN;
  const float4* dg4 = (const float4*)dg;
  float mxl = -1e30f;
  #pragma unroll
  for (int j = 0; j < 4; ++j) {
    const float4 v = dg4[lane + 64*j];
    mxl = fmaxf(fmaxf(v.x, v.y), fmaxf(fmaxf(v.z, v.w), mxl));
  }
  #pragma unroll
  for (int off = 1; off < 64; off <<= 1) mxl = fmaxf(mxl, __shfl_xor(mxl, off));
  const float maxd = mxl;

  const int r0 = row0 + colr, r1 = r0 + 16;
  const float s0 = s_arr[(size_t)bch*NN + r0];
  const float s1 = s_arr[(size_t)bch*NN + r1];
  const float so0 = s0 + maxd, so1 = s1 + maxd;
  const float offs0 = fmaxf(so0, 0.2f*so0);   // >= lrelu(s0+d) for all d
  const float offs1 = fmaxf(so1, 0.2f*so1);
  const float sA0 = s0 - offs0, sB0 = 0.2f*s0 - offs0;
  const float sA1 = s1 - offs1, sB1 = 0.2f*s1 - offs1;

  unsigned long long m0[4], m1[4];
  {
    const unsigned long long* bm0 = bmg + ((size_t)b*NN + r0)*16 + w*4;
    const unsigned long long* bm1 = bmg + ((size_t)b*NN + r1)*16 + w*4;
    #pragma unroll
    for (int j = 0; j < 4; ++j) { m0[j] = bm0[j]; m1[j] = bm1[j]; }
  }

  const _Float16* Bg = HpT + (size_t)bch*64*NN;
  const int kbase = w*256;
  const _Float16* Bp = Bg + kbase + quad*8;

  f32x4 acc[2][4], accs[2];
  #pragma unroll
  for (int rt = 0; rt < 2; ++rt) {
    accs[rt] = (f32x4){0.f,0.f,0.f,0.f};
    #pragma unroll
    for (int ft = 0; ft < 4; ++ft) acc[rt][ft] = (f32x4){0.f,0.f,0.f,0.f};
  }
  f16x8 ones;
  #pragma unroll
  for (int i = 0; i < 8; ++i) ones[i] = (_Float16)1.f;

  // prefetch ks=0
  f16x8 Bc[4];
  #pragma unroll
  for (int ft = 0; ft < 4; ++ft) Bc[ft] = *(const f16x8*)(Bp + (size_t)(ft*16 + colr)*NN);
  float4 dc0 = *(const float4*)(dg + kbase + quad*8);
  float4 dc1 = *(const float4*)(dg + kbase + quad*8 + 4);

  #pragma unroll
  for (int ks = 0; ks < 8; ++ks) {
    f16x8 Bn[4]; float4 dn0, dn1;
    if (ks < 7) {
      #pragma unroll
      for (int ft = 0; ft < 4; ++ft)
        Bn[ft] = *(const f16x8*)(Bp + (size_t)(ft*16 + colr)*NN + (ks+1)*32);
      dn0 = *(const float4*)(dg + kbase + (ks+1)*32 + quad*8);
      dn1 = *(const float4*)(dg + kbase + (ks+1)*32 + quad*8 + 4);
    }
    const unsigned mb0 = (unsigned)((m0[ks >> 1] >> ((ks & 1)*32 + quad*8)) & 0xFFull);
    const unsigned mb1 = (unsigned)((m1[ks >> 1] >> ((ks & 1)*32 + quad*8)) & 0xFFull);
    const float dd[8] = {dc0.x, dc0.y, dc0.z, dc0.w, dc1.x, dc1.y, dc1.z, dc1.w};
    union { f16x8 v; h16x2 h[4]; } A0, A1;
    #pragma unroll
    for (int jp = 0; jp < 4; ++jp) {
      float p0[2], p1[2];
      #pragma unroll
      for (int jj = 0; jj < 2; ++jj) {
        const int j = jp*2 + jj;
        const float dj = dd[j];
        const float l0 = fmaxf(sA0 + dj, fmaf(0.2f, dj, sB0));  // log2e-scaled domain
        const float l1 = fmaxf(sA1 + dj, fmaf(0.2f, dj, sB1));
        p0[jj] = ((mb0 >> j) & 1u) ? fexp2(l0) : 0.f;
        p1[jj] = ((mb1 >> j) & 1u) ? fexp2(l1) : 0.f;
      }
      A0.h[jp] = __builtin_amdgcn_cvt_pkrtz(p0[0], p0[1]);
      A1.h[jp] = __builtin_amdgcn_cvt_pkrtz(p1[0], p1[1]);
    }
    #pragma unroll
    for (int ft = 0; ft < 4; ++ft) {
      acc[0][ft] = __builtin_amdgcn_mfma_f32_16x16x32_f16(A0.v, Bc[ft], acc[0][ft], 0, 0, 0);
      acc[1][ft] = __builtin_amdgcn_mfma_f32_16x16x32_f16(A1.v, Bc[ft], acc[1][ft], 0, 0, 0);
    }
    accs[0] = __builtin_amdgcn_mfma_f32_16x16x32_f16(A0.v, ones, accs[0], 0, 0, 0);
    accs[1] = __builtin_amdgcn_mfma_f32_16x16x32_f16(A1.v, ones, accs[1], 0, 0, 0);
    if (ks < 7) {
      #pragma unroll
      for (int ft = 0; ft < 4; ++ft) Bc[ft] = Bn[ft];
      dc0 = dn0; dc1 = dn1;
    }
  }

  if (colr == 0) {
    #pragma unroll
    for (int i = 0; i < 4; ++i) {
      dsP[w][quad*4 + i] = accs[0][i];
      dsP[w][16 + quad*4 + i] = accs[1][i];
    }
  }
  float* pw = partials[w];
  #pragma unroll
  for (int rt = 0; rt < 2; ++rt)
    #pragma unroll
    for (int ft = 0; ft < 4; ++ft)
      #pragma unroll
      for (int i = 0; i < 4; ++i)
        pw[(rt*16 + quad*4 + i)*68 + ft*16 + colr] = acc[rt][ft][i];
  __syncthreads();

  const int r = t >> 3, f0 = (t & 7)*8;
  const float dsum = dsP[0][r] + dsP[1][r] + dsP[2][r] + dsP[3][r];
  const float inv = 1.f / dsum;
  float4 c0 = {0.f,0.f,0.f,0.f}, c1 = {0.f,0.f,0.f,0.f};
  #pragma unroll
  for (int w4 = 0; w4 < 4; ++w4) {
    const float* base = &partials[w4][r*68 + f0];
    const float4 a0 = *(const float4*)base;
    const float4 a1 = *(const float4*)(base + 4);
    c0.x += a0.x; c0.y += a0.y; c0.z += a0.z; c0.w += a0.w;
    c1.x += a1.x; c1.y += a1.y; c1.z += a1.z; c1.w += a1.w;
  }
  const float cv[8] = {c0.x,c0.y,c0.z,c0.w, c1.x,c1.y,c1.z,c1.w};
  f16x8 o;
  #pragma unroll
  for (int i = 0; i < 8; ++i) {
    float v = cv[i] * inv;
    if (LAYER == 1) v = v > 0.f ? v : expm1f(v);
    o[i] = (_Float16)v;
  }
  const int bc = bch / HH, h = bch % HH;
  if (LAYER == 1)
    *(f16x8*)(outp + ((size_t)bc*NN + row0 + r)*512 + h*64 + f0) = o;
  else
    *(f16x8*)(outp + ((size_t)bch*NN + row0 + r)*64 + f0) = o;
}

// ---------------- Mean over heads (f16 in) -> fp32 out ----------------
__global__ __launch_bounds__(256) void reduce_heads(
    const _Float16* __restrict__ out2, float* __restrict__ out)
{
  const int o = blockIdx.x*256 + threadIdx.x;
  const int f = o & 63;
  const int n = (o >> 6) & (NN - 1);
  const int bc = o >> 16;
  float acc = 0.f;
  #pragma unroll
  for (int h = 0; h < HH; ++h)
    acc += (float)out2[(((size_t)bc*HH + h)*NN + n)*FFV + f];
  out[o] = acc * 0.125f;
}

extern "C" void kernel_launch(void* const* d_in, const int* in_sizes, int n_in,
                              void* d_out, int out_size, void* d_ws, size_t ws_size,
                              hipStream_t stream)
{
  const float* x   = (const float*)d_in[0];
  const int*   adj = (const int*)d_in[1];
  const float* w1  = (const float*)d_in[2];
  const float* as1 = (const float*)d_in[3];
  const float* ad1 = (const float*)d_in[4];
  const float* w2  = (const float*)d_in[5];
  const float* as2 = (const float*)d_in[6];
  const float* ad2 = (const float*)d_in[7];

  char* w8 = (char*)d_ws;
  _Float16* HpT = (_Float16*)(w8);                         // 4 MB  [bch][64][N]
  _Float16* XB  = (_Float16*)(w8 + (4u<<20));              // 4 MB  x1 [bc][N][512] then out2 [bch][N][64]
  _Float16* w2T = (_Float16*)(w8 + (8u<<20));              // 1 MB   [ch][64][512]
  float* s_v = (float*)(w8 + (10u<<20));                   // 128 KB (log2e-scaled)
  float* d_v = (float*)(w8 + (10u<<20) + SVN*4);           // 128 KB (log2e-scaled)
  unsigned long long* bmg = (unsigned long long*)(w8 + (10u<<20) + SVN*8);  // 256 KB

  proj1_fused<<<1408, 256, 0, stream>>>(x, adj, w1, w2, as1, ad1, w2T, bmg, HpT, s_v, d_v);
  attn_mfma<1><<<dim3(BCHN, NN/32), 256, 0, stream>>>(HpT, s_v, d_v, bmg, XB);
  proj_mfma<512><<<dim3(NN/32, BCHN), 256, 0, stream>>>(XB, w2T, as2, ad2, HpT, s_v, d_v);
  attn_mfma<2><<<dim3(BCHN, NN/32), 256, 0, stream>>>(HpT, s_v, d_v, bmg, XB);
  reduce_heads<<<dim3((unsigned)(out_size/256)), 256, 0, stream>>>(XB, (float*)d_out);
}